// Round 1
// baseline (1578.740 us; speedup 1.0000x reference)
//
#include <hip/hip_runtime.h>

// Problem constants (reference: VOCAB=32000, H=1024, L=256, B=64)
#define Hh   1024
#define Ll   256
#define Bb   64
#define SENT 0xAAAAAAAAu

// ---------- helpers ----------
__device__ __forceinline__ unsigned int bf16_rne(float f) {
  unsigned int u = __float_as_uint(f);
  return (u + 0x7FFFu + ((u >> 16) & 1u)) >> 16;
}
__device__ __forceinline__ float bf_lo(unsigned int w) { return __uint_as_float(w << 16); }
__device__ __forceinline__ float bf_hi(unsigned int w) { return __uint_as_float(w & 0xFFFF0000u); }
__device__ __forceinline__ float sigf(float x) { return 1.0f / (1.0f + __expf(-x)); }
__device__ __forceinline__ float tanh_fast(float x) {
  float e = __expf(2.0f * x);
  return 1.0f - 2.0f / (e + 1.0f);
}

// ---------- K1: gi[t][j] = emb[x[t,0]] . w_ih[j] + b_ih[j] (+ b_hh[j] for j<2048) ----------
// grid 256 blocks x 256 thr; block owns 12 j-rows; thread owns one t.
__global__ __launch_bounds__(256) void k1_gi(const int* __restrict__ x,
                                             const float* __restrict__ emb,
                                             const float* __restrict__ w_ih,
                                             const float* __restrict__ b_ih,
                                             const float* __restrict__ b_hh,
                                             float* __restrict__ gi)
{
  const int j0 = blockIdx.x * 12;
  const int t  = threadIdx.x;                 // 0..255
  const int idx = x[t * Bb];                  // x[t][0]
  const float* e_row = emb + (size_t)idx * Hh;

  float acc[12];
#pragma unroll
  for (int j = 0; j < 12; ++j) {
    const int jj = j0 + j;
    float b = b_ih[jj];
    if (jj < 2048) b += b_hh[jj];             // fold b_hh for r,z gates only
    acc[j] = b;
  }

  for (int kc = 0; kc < Hh; kc += 16) {
    float4 v0 = *(const float4*)(e_row + kc + 0);
    float4 v1 = *(const float4*)(e_row + kc + 4);
    float4 v2 = *(const float4*)(e_row + kc + 8);
    float4 v3 = *(const float4*)(e_row + kc + 12);
    float e[16] = {v0.x, v0.y, v0.z, v0.w, v1.x, v1.y, v1.z, v1.w,
                   v2.x, v2.y, v2.z, v2.w, v3.x, v3.y, v3.z, v3.w};
#pragma unroll
    for (int j = 0; j < 12; ++j) {
      const float* wr = w_ih + (size_t)(j0 + j) * Hh + kc;  // wave-uniform -> s_load
#pragma unroll
      for (int i = 0; i < 16; ++i) acc[j] = fmaf(e[i], wr[i], acc[j]);
    }
  }

  float* dst = gi + (size_t)t * 3072 + j0;
#pragma unroll
  for (int j = 0; j < 12; j += 4)
    *(float4*)(dst + j) = make_float4(acc[j], acc[j + 1], acc[j + 2], acc[j + 3]);
}

// ---------- K2: persistent recurrence ----------
// grid 128 blocks x 512 thr (8 waves). Block g owns h-elements [8g, 8g+8); wave w computes
// element hj = 8g+w. w_hh rows for (r,z,n) of the 8 elements live in LDS as packed bf16
// pairs: wlds[e*3+gate][p*64+lane] = bf16(row[2p*64+lane]) | bf16(row[(2p+1)*64+lane])<<16.
// Sync: sentinel-in-data. hseq pre-memset to 0xAA; producers store h with agent-scope
// relaxed atomics (to L3 coherence point), wave 0 polls until all 1024 elems valid.
__global__ __launch_bounds__(512) void k2_rec(const float* __restrict__ w_hh,
                                              const float* __restrict__ b_hh,
                                              const float* __restrict__ gi,
                                              unsigned int* __restrict__ hseq)
{
  __shared__ unsigned int wlds[24][512];  // 48 KB packed bf16
  __shared__ float hlds[Hh];              // 4 KB

  const int g    = blockIdx.x;
  const int tid  = threadIdx.x;
  const int wv   = tid >> 6;              // team 0..7
  const int lane = tid & 63;
  const int hj   = g * 8 + wv;            // this team's h element

  // ---- Phase A: stage weights (bf16, RNE) + zero h ----
  {
    const int p = tid >> 6, l = tid & 63;
#pragma unroll
    for (int r = 0; r < 24; ++r) {
      const int e = r / 3, gate = r % 3;
      const float* src = w_hh + (size_t)(gate * Hh + g * 8 + e) * Hh;
      float a = src[(2 * p) * 64 + l];
      float b = src[(2 * p + 1) * 64 + l];
      wlds[r][p * 64 + l] = bf16_rne(a) | (bf16_rne(b) << 16);
    }
    hlds[tid] = 0.0f;
    hlds[512 + tid] = 0.0f;
  }
  __syncthreads();

  const float bhh_n = b_hh[2048 + hj];
  const unsigned int* wbase = &wlds[wv * 3][0];  // 3 contiguous rows of 512 uints

  for (int t = 0; t < Ll; ++t) {
    // gi prefetch (wave-uniform scalar loads; independent of the poll)
    const float gi_r = gi[(size_t)t * 3072 + hj];
    const float gi_z = gi[(size_t)t * 3072 + 1024 + hj];
    const float gi_n = gi[(size_t)t * 3072 + 2048 + hj];

    if (t > 0) {
      if (wv == 0) {
        unsigned int* hb = hseq + (size_t)(t - 1) * Hh;
        unsigned int u[16];
        for (;;) {
          bool ok = true;
#pragma unroll
          for (int i = 0; i < 16; ++i) {
            u[i] = __hip_atomic_load(hb + i * 64 + lane, __ATOMIC_RELAXED,
                                     __HIP_MEMORY_SCOPE_AGENT);
            ok &= (u[i] != SENT);
          }
          if (__all(ok)) break;   // collective exit: whole h[t-1] visible =>
        }                         //   all teams (incl. ours) finished reading hlds
#pragma unroll
        for (int i = 0; i < 16; ++i) hlds[i * 64 + lane] = __uint_as_float(u[i]);
      }
      __syncthreads();
    }

    // gh dot products: lane owns k = {i*64+lane}
    float ar = 0.f, az = 0.f, an = 0.f;
#pragma unroll
    for (int p = 0; p < 8; ++p) {
      const float h0 = hlds[(2 * p) * 64 + lane];
      const float h1 = hlds[(2 * p + 1) * 64 + lane];
      const unsigned int wr = wbase[0 * 512 + p * 64 + lane];
      const unsigned int wz = wbase[1 * 512 + p * 64 + lane];
      const unsigned int wn = wbase[2 * 512 + p * 64 + lane];
      ar = fmaf(h0, bf_lo(wr), ar); ar = fmaf(h1, bf_hi(wr), ar);
      az = fmaf(h0, bf_lo(wz), az); az = fmaf(h1, bf_hi(wz), az);
      an = fmaf(h0, bf_lo(wn), an); an = fmaf(h1, bf_hi(wn), an);
    }
#pragma unroll
    for (int m = 1; m < 64; m <<= 1) {
      ar += __shfl_xor(ar, m, 64);
      az += __shfl_xor(az, m, 64);
      an += __shfl_xor(an, m, 64);
    }

    const float hp = hlds[hj];                 // broadcast read (zeros at t=0)
    const float r  = sigf(ar + gi_r);          // b_ih+b_hh folded into gi_r
    const float z  = sigf(az + gi_z);
    const float n  = tanh_fast(gi_n + r * (an + bhh_n));
    const float h2 = (1.0f - z) * n + z * hp;

    if (lane == 0) {
      unsigned int bits = __float_as_uint(h2);
      if (bits == SENT) bits ^= 1u;            // never store the sentinel
      __hip_atomic_store(hseq + (size_t)t * Hh + hj, bits, __ATOMIC_RELAXED,
                         __HIP_MEMORY_SCOPE_AGENT);
    }
  }
}

// ---------- K3: feat broadcast write + w_out dot partials ----------
// grid 1024 x 256. feat[b][i] = hseq[i] for all b. Blocks 0..63 also accumulate the
// w_out dot into *acc via atomicAdd.
__global__ __launch_bounds__(256) void k3_out(const float* __restrict__ hseq_f,
                                              const float* __restrict__ w_out,
                                              float* __restrict__ outbuf,
                                              float* __restrict__ acc)
{
  const int gtid = blockIdx.x * 256 + threadIdx.x;
  const float4* src = (const float4*)hseq_f;    // 65536 float4
  float4* dst = (float4*)outbuf;
  for (int q = gtid; q < 64 * 65536; q += 1024 * 256) {
    const int b = q >> 16, i4 = q & 65535;
    dst[(size_t)b * 65536 + i4] = src[i4];
  }

  if (blockIdx.x < 64) {
    const int b4 = blockIdx.x * 1024;           // 1024 float4 slice
    float p = 0.f;
#pragma unroll
    for (int k = 0; k < 4; ++k) {
      const int i4 = b4 + k * 256 + threadIdx.x;
      const float4 h = src[i4];
      const float4 w = ((const float4*)w_out)[i4];
      p += h.x * w.x + h.y * w.y + h.z * w.z + h.w * w.w;
    }
#pragma unroll
    for (int m = 1; m < 64; m <<= 1) p += __shfl_xor(p, m, 64);
    __shared__ float sp[4];
    if ((threadIdx.x & 63) == 0) sp[threadIdx.x >> 6] = p;
    __syncthreads();
    if (threadIdx.x == 0) atomicAdd(acc, sp[0] + sp[1] + sp[2] + sp[3]);
  }
}

// ---------- K4: out[b] = sigmoid(acc + b_out), identical for all b ----------
__global__ void k4_fin(const float* __restrict__ acc, const float* __restrict__ b_out,
                       float* __restrict__ outbuf)
{
  const float s = sigf(acc[0] + b_out[0]);
  outbuf[(size_t)16777216 + threadIdx.x] = s;   // 64 threads
}

// ---------- launch ----------
extern "C" void kernel_launch(void* const* d_in, const int* in_sizes, int n_in,
                              void* d_out, int out_size, void* d_ws, size_t ws_size,
                              hipStream_t stream) {
  const int*   x     = (const int*)d_in[0];
  const float* emb   = (const float*)d_in[1];
  const float* w_ih  = (const float*)d_in[2];
  const float* w_hh  = (const float*)d_in[3];
  const float* b_ih  = (const float*)d_in[4];
  const float* b_hh  = (const float*)d_in[5];
  const float* w_out = (const float*)d_in[6];
  const float* b_out = (const float*)d_in[7];
  float* out = (float*)d_out;

  char* ws = (char*)d_ws;
  float*        gi   = (float*)ws;                          // 3,145,728 B
  unsigned int* hseq = (unsigned int*)(ws + 3145728);       // 1,048,576 B
  float*        acc  = (float*)(ws + 3145728 + 1048576);    // 4 B

  // Sentinel init (cannot rely on harness poison on the first call) + dot accumulator.
  hipMemsetAsync(hseq, 0xAA, (size_t)Ll * Hh * 4, stream);
  hipMemsetAsync(acc, 0, 4, stream);

  hipLaunchKernelGGL(k1_gi,  dim3(256),  dim3(256), 0, stream, x, emb, w_ih, b_ih, b_hh, gi);
  hipLaunchKernelGGL(k2_rec, dim3(128),  dim3(512), 0, stream, w_hh, b_hh, gi, hseq);
  hipLaunchKernelGGL(k3_out, dim3(1024), dim3(256), 0, stream, (const float*)hseq, w_out, out, acc);
  hipLaunchKernelGGL(k4_fin, dim3(1),    dim3(64),  0, stream, acc, b_out, out);
}

// Round 2
// 1402.520 us; speedup vs baseline: 1.1256x; 1.1256x over previous
//
#include <hip/hip_runtime.h>

// Problem constants (reference: VOCAB=32000, H=1024, L=256, B=64)
#define SENT 0xAAAAAAAAu

// ---------- helpers ----------
__device__ __forceinline__ unsigned int bf16_rne(float f) {
  unsigned int u = __float_as_uint(f);
  return (u + 0x7FFFu + ((u >> 16) & 1u)) >> 16;
}
__device__ __forceinline__ float bf_lo(unsigned int w) { return __uint_as_float(w << 16); }
__device__ __forceinline__ float bf_hi(unsigned int w) { return __uint_as_float(w & 0xFFFF0000u); }
__device__ __forceinline__ float sigf(float x) { return 1.0f / (1.0f + __expf(-x)); }
__device__ __forceinline__ float tanh_fast(float x) {
  float e = __expf(2.0f * x);
  return 1.0f - 2.0f / (e + 1.0f);
}

// ---------- K0: gather embedding rows for batch element 0 into contiguous e_buf ----------
// grid 256 (block = t), 256 thr; e_buf[t][k] = emb[x[t][0]][k]
__global__ __launch_bounds__(256) void k0_gather(const int* __restrict__ x,
                                                 const float* __restrict__ emb,
                                                 float* __restrict__ e_buf)
{
  const int t = blockIdx.x;
  const int idx = x[t * 64];
  ((float4*)e_buf)[t * 256 + threadIdx.x] =
      ((const float4*)(emb + (size_t)idx * 1024))[threadIdx.x];
}

// ---------- K1: gi[t][j] = e_buf[t] . w_ih[j] + b_ih[j] (+ b_hh[j] for j<2048) ----------
// grid 768 blocks (4 rows each) x 256 thr (thread = t). 3 blocks/CU -> 12 waves/CU for
// latency hiding (round-1 version ran 1 wave/SIMD and stalled on e-row loads).
__global__ __launch_bounds__(256) void k1_gi(const float* __restrict__ e_buf,
                                             const float* __restrict__ w_ih,
                                             const float* __restrict__ b_ih,
                                             const float* __restrict__ b_hh,
                                             float* __restrict__ gi)
{
  const int j0 = blockIdx.x * 4;
  const int t  = threadIdx.x;
  const float* er = e_buf + (size_t)t * 1024;

  float acc[4];
#pragma unroll
  for (int j = 0; j < 4; ++j) {
    const int jj = j0 + j;
    acc[j] = b_ih[jj] + (jj < 2048 ? b_hh[jj] : 0.0f);  // fold b_hh for r,z gates
  }

  for (int kc = 0; kc < 1024; kc += 16) {
    const float4 e0 = *(const float4*)(er + kc);
    const float4 e1 = *(const float4*)(er + kc + 4);
    const float4 e2 = *(const float4*)(er + kc + 8);
    const float4 e3 = *(const float4*)(er + kc + 12);
    const float e[16] = {e0.x, e0.y, e0.z, e0.w, e1.x, e1.y, e1.z, e1.w,
                         e2.x, e2.y, e2.z, e2.w, e3.x, e3.y, e3.z, e3.w};
#pragma unroll
    for (int j = 0; j < 4; ++j) {
      const float* w = w_ih + (size_t)(j0 + j) * 1024 + kc;  // wave-uniform -> s_load
#pragma unroll
      for (int i = 0; i < 16; ++i) acc[j] = fmaf(e[i], w[i], acc[j]);
    }
  }
  *(float4*)(gi + (size_t)t * 3072 + j0) = make_float4(acc[0], acc[1], acc[2], acc[3]);
}

// ---------- K2: persistent recurrence ----------
// grid 128 x 512 (8 waves). Block g owns h elements [8g, 8g+8); wave wv computes hj=8g+wv.
// w_hh in LDS as packed bf16, layout matched to the hlds read pattern:
//   lane l owns k = j*256 + l*4 + c (j=0..3, c=0..3);
//   wlds[(el*3+gate)*512 + j*128 + l*2 + (c>>1)] packs bf16(k_even)|bf16(k_odd)<<16.
// Sync: sentinel-in-data. Producers store h bits with one relaxed agent atomic per wave.
// Consumers (wave 0) poll with COALESCED PLAIN dwordx4 loads, preceded each round by an
// agent acquire fence (buffer_inv: invalidate L1/L2 so re-reads reach L3). Data-as-flag
// needs no acquire ordering -- any non-sentinel word IS the payload; the fence is only
// for freshness. Bounded spin falls back to atomic loads to guarantee liveness.
__global__ __launch_bounds__(512) void k2_rec(const float* __restrict__ w_hh,
                                              const float* __restrict__ b_hh,
                                              const float* __restrict__ gi,
                                              unsigned int* __restrict__ hseq)
{
  __shared__ unsigned int wlds[12288];  // 48 KB
  __shared__ unsigned int hlds[1024];   // 4 KB

  const int g    = blockIdx.x;
  const int tid  = threadIdx.x;
  const int wv   = tid >> 6;
  const int lane = tid & 63;
  const int hj   = __builtin_amdgcn_readfirstlane(g * 8 + wv);  // force SGPR -> s_loads for gi

  // ---- stage weights (coalesced float2 read; LDS write index collapses to r*512+tid) ----
#pragma unroll
  for (int r = 0; r < 24; ++r) {
    const int el = r / 3, gate = r % 3;
    const float2 v = *(const float2*)(w_hh + (size_t)(gate * 1024 + g * 8 + el) * 1024 + tid * 2);
    wlds[r * 512 + tid] = bf16_rne(v.x) | (bf16_rne(v.y) << 16);
  }
  __syncthreads();

  const float bhh_n = b_hh[2048 + hj];
  float hp = 0.0f;

  for (int t = 0; t < 256; ++t) {
    // gi prefetch (wave-uniform scalar loads; overlap the poll)
    const float gi_r = gi[(size_t)t * 3072 + hj];
    const float gi_z = gi[(size_t)t * 3072 + 1024 + hj];
    const float gi_n = gi[(size_t)t * 3072 + 2048 + hj];

    float ar = 0.f, az = 0.f, an = 0.f;

    if (t > 0) {
      if (wv == 0) {
        const unsigned int* hb = hseq + (size_t)(t - 1) * 1024;
        uint4 a0, a1, a2, a3;
        int spin = 0;
        for (;;) {
          if (spin < 4096) {
            __builtin_amdgcn_fence(__ATOMIC_ACQUIRE, "agent");  // inv L1+L2 -> fresh re-read
            a0 = *(const uint4*)(hb +       lane * 4);
            a1 = *(const uint4*)(hb + 256 + lane * 4);
            a2 = *(const uint4*)(hb + 512 + lane * 4);
            a3 = *(const uint4*)(hb + 768 + lane * 4);
          } else {  // liveness fallback: guaranteed-fresh atomic loads
            const unsigned int* p = hb + lane * 4;
            a0.x = __hip_atomic_load(p + 0,   __ATOMIC_RELAXED, __HIP_MEMORY_SCOPE_AGENT);
            a0.y = __hip_atomic_load(p + 1,   __ATOMIC_RELAXED, __HIP_MEMORY_SCOPE_AGENT);
            a0.z = __hip_atomic_load(p + 2,   __ATOMIC_RELAXED, __HIP_MEMORY_SCOPE_AGENT);
            a0.w = __hip_atomic_load(p + 3,   __ATOMIC_RELAXED, __HIP_MEMORY_SCOPE_AGENT);
            a1.x = __hip_atomic_load(p + 256, __ATOMIC_RELAXED, __HIP_MEMORY_SCOPE_AGENT);
            a1.y = __hip_atomic_load(p + 257, __ATOMIC_RELAXED, __HIP_MEMORY_SCOPE_AGENT);
            a1.z = __hip_atomic_load(p + 258, __ATOMIC_RELAXED, __HIP_MEMORY_SCOPE_AGENT);
            a1.w = __hip_atomic_load(p + 259, __ATOMIC_RELAXED, __HIP_MEMORY_SCOPE_AGENT);
            a2.x = __hip_atomic_load(p + 512, __ATOMIC_RELAXED, __HIP_MEMORY_SCOPE_AGENT);
            a2.y = __hip_atomic_load(p + 513, __ATOMIC_RELAXED, __HIP_MEMORY_SCOPE_AGENT);
            a2.z = __hip_atomic_load(p + 514, __ATOMIC_RELAXED, __HIP_MEMORY_SCOPE_AGENT);
            a2.w = __hip_atomic_load(p + 515, __ATOMIC_RELAXED, __HIP_MEMORY_SCOPE_AGENT);
            a3.x = __hip_atomic_load(p + 768, __ATOMIC_RELAXED, __HIP_MEMORY_SCOPE_AGENT);
            a3.y = __hip_atomic_load(p + 769, __ATOMIC_RELAXED, __HIP_MEMORY_SCOPE_AGENT);
            a3.z = __hip_atomic_load(p + 770, __ATOMIC_RELAXED, __HIP_MEMORY_SCOPE_AGENT);
            a3.w = __hip_atomic_load(p + 771, __ATOMIC_RELAXED, __HIP_MEMORY_SCOPE_AGENT);
          }
          const bool ok =
              (a0.x != SENT) & (a0.y != SENT) & (a0.z != SENT) & (a0.w != SENT) &
              (a1.x != SENT) & (a1.y != SENT) & (a1.z != SENT) & (a1.w != SENT) &
              (a2.x != SENT) & (a2.y != SENT) & (a2.z != SENT) & (a2.w != SENT) &
              (a3.x != SENT) & (a3.y != SENT) & (a3.z != SENT) & (a3.w != SENT);
          if (__all(ok)) break;  // whole h[t-1] visible => all waves (incl. ours) past
          ++spin;                //   their hlds reads for step t-1 -> safe to overwrite
        }
        *(uint4*)&hlds[      lane * 4] = a0;
        *(uint4*)&hlds[256 + lane * 4] = a1;
        *(uint4*)&hlds[512 + lane * 4] = a2;
        *(uint4*)&hlds[768 + lane * 4] = a3;
      }
      __syncthreads();

      const int base0 = wv * 1536 + lane * 2;
#pragma unroll
      for (int j = 0; j < 4; ++j) {
        const uint4 hu = *(const uint4*)&hlds[j * 256 + lane * 4];
        const float h0 = __uint_as_float(hu.x), h1 = __uint_as_float(hu.y);
        const float h2v = __uint_as_float(hu.z), h3 = __uint_as_float(hu.w);
        const int b = base0 + j * 128;
        const uint2 wr = *(const uint2*)&wlds[b];
        const uint2 wz = *(const uint2*)&wlds[b + 512];
        const uint2 wn = *(const uint2*)&wlds[b + 1024];
        ar = fmaf(h0, bf_lo(wr.x), ar); ar = fmaf(h1, bf_hi(wr.x), ar);
        ar = fmaf(h2v, bf_lo(wr.y), ar); ar = fmaf(h3, bf_hi(wr.y), ar);
        az = fmaf(h0, bf_lo(wz.x), az); az = fmaf(h1, bf_hi(wz.x), az);
        az = fmaf(h2v, bf_lo(wz.y), az); az = fmaf(h3, bf_hi(wz.y), az);
        an = fmaf(h0, bf_lo(wn.x), an); an = fmaf(h1, bf_hi(wn.x), an);
        an = fmaf(h2v, bf_lo(wn.y), an); an = fmaf(h3, bf_hi(wn.y), an);
      }
#pragma unroll
      for (int m = 1; m < 64; m <<= 1) {
        ar += __shfl_xor(ar, m, 64);
        az += __shfl_xor(az, m, 64);
        an += __shfl_xor(an, m, 64);
      }
    }

    const float r = sigf(ar + gi_r);                    // b_ih+b_hh folded into gi_r/gi_z
    const float z = sigf(az + gi_z);
    const float n = tanh_fast(gi_n + r * (an + bhh_n));
    const float h2 = (1.0f - z) * n + z * hp;

    unsigned int bits = __float_as_uint(h2);
    if (bits == SENT) bits ^= 1u;                       // never store the sentinel
    if (lane == 0)
      __hip_atomic_store(hseq + (size_t)t * 1024 + hj, bits, __ATOMIC_RELAXED,
                         __HIP_MEMORY_SCOPE_AGENT);
    hp = __uint_as_float(bits);                         // carry own element in-register
  }
}

// ---------- K3: feat broadcast write + w_out dot partials ----------
__global__ __launch_bounds__(256) void k3_out(const float* __restrict__ hseq_f,
                                              const float* __restrict__ w_out,
                                              float* __restrict__ outbuf,
                                              float* __restrict__ acc)
{
  const int gtid = blockIdx.x * 256 + threadIdx.x;
  const float4* src = (const float4*)hseq_f;    // 65536 float4
  float4* dst = (float4*)outbuf;
  for (int q = gtid; q < 64 * 65536; q += 1024 * 256) {
    const int b = q >> 16, i4 = q & 65535;
    dst[(size_t)b * 65536 + i4] = src[i4];
  }

  if (blockIdx.x < 64) {
    const int b4 = blockIdx.x * 1024;
    float p = 0.f;
#pragma unroll
    for (int k = 0; k < 4; ++k) {
      const int i4 = b4 + k * 256 + threadIdx.x;
      const float4 h = src[i4];
      const float4 w = ((const float4*)w_out)[i4];
      p += h.x * w.x + h.y * w.y + h.z * w.z + h.w * w.w;
    }
#pragma unroll
    for (int m = 1; m < 64; m <<= 1) p += __shfl_xor(p, m, 64);
    __shared__ float sp[4];
    if ((threadIdx.x & 63) == 0) sp[threadIdx.x >> 6] = p;
    __syncthreads();
    if (threadIdx.x == 0) atomicAdd(acc, sp[0] + sp[1] + sp[2] + sp[3]);
  }
}

// ---------- K4: out[b] = sigmoid(acc + b_out) for all 64 b ----------
__global__ void k4_fin(const float* __restrict__ acc, const float* __restrict__ b_out,
                       float* __restrict__ outbuf)
{
  const float s = sigf(acc[0] + b_out[0]);
  outbuf[(size_t)16777216 + threadIdx.x] = s;
}

// ---------- launch ----------
extern "C" void kernel_launch(void* const* d_in, const int* in_sizes, int n_in,
                              void* d_out, int out_size, void* d_ws, size_t ws_size,
                              hipStream_t stream) {
  const int*   x     = (const int*)d_in[0];
  const float* emb   = (const float*)d_in[1];
  const float* w_ih  = (const float*)d_in[2];
  const float* w_hh  = (const float*)d_in[3];
  const float* b_ih  = (const float*)d_in[4];
  const float* b_hh  = (const float*)d_in[5];
  const float* w_out = (const float*)d_in[6];
  const float* b_out = (const float*)d_in[7];
  float* out = (float*)d_out;

  char* ws = (char*)d_ws;
  float*        gi    = (float*)ws;                       // 3,145,728 B
  unsigned int* hseq  = (unsigned int*)(ws + 3145728);    // 1,048,576 B (aliases e_buf)
  float*        e_buf = (float*)(ws + 3145728);           // e_buf dead before hseq memset
  float*        acc   = (float*)(ws + 4194304);           // 4 B

  hipLaunchKernelGGL(k0_gather, dim3(256), dim3(256), 0, stream, x, emb, e_buf);
  hipLaunchKernelGGL(k1_gi,     dim3(768), dim3(256), 0, stream, e_buf, w_ih, b_ih, b_hh, gi);

  // Sentinel init AFTER k1 (e_buf aliases hseq); stream-ordered before k2.
  hipMemsetAsync(hseq, 0xAA, (size_t)256 * 1024 * 4, stream);
  hipMemsetAsync(acc, 0, 4, stream);

  hipLaunchKernelGGL(k2_rec, dim3(128),  dim3(512), 0, stream, w_hh, b_hh, gi, hseq);
  hipLaunchKernelGGL(k3_out, dim3(1024), dim3(256), 0, stream, (const float*)hseq, w_out, out, acc);
  hipLaunchKernelGGL(k4_fin, dim3(1),    dim3(64),  0, stream, acc, b_out, out);
}

// Round 3
// 1026.674 us; speedup vs baseline: 1.5377x; 1.3661x over previous
//
#include <hip/hip_runtime.h>

// Problem: VOCAB=32000, H=1024, L=256, B=64.  Only batch row 0 matters
// (reference broadcasts hs[:, :1, :]), so this is a single-sequence GRU.
#define SENT 0xAAAAAAAAu

__device__ __forceinline__ float sigf(float x) { return 1.0f / (1.0f + __expf(-x)); }
__device__ __forceinline__ float tanh_fast(float x) {
  float e = __expf(2.0f * x);
  return 1.0f - 2.0f / (e + 1.0f);
}

// ---------- K1: gi[t][j] = emb[x[t][0]] . w_ih[j] + b_ih[j] (+ b_hh[j] for j<2048) ----------
// grid 768 blocks (4 j-rows each) x 256 thr (thread = t). 3 blocks/CU for latency hiding.
__global__ __launch_bounds__(256) void k1_gi(const int* __restrict__ x,
                                             const float* __restrict__ emb,
                                             const float* __restrict__ w_ih,
                                             const float* __restrict__ b_ih,
                                             const float* __restrict__ b_hh,
                                             float* __restrict__ gi)
{
  const int j0 = blockIdx.x * 4;
  const int t  = threadIdx.x;
  const int idx = x[t * 64];                       // x[t][0]
  const float* er = emb + (size_t)idx * 1024;

  float acc[4];
#pragma unroll
  for (int j = 0; j < 4; ++j) {
    const int jj = j0 + j;
    acc[j] = b_ih[jj] + (jj < 2048 ? b_hh[jj] : 0.0f);  // fold b_hh for r,z gates
  }

  for (int kc = 0; kc < 1024; kc += 16) {
    const float4 e0 = *(const float4*)(er + kc);
    const float4 e1 = *(const float4*)(er + kc + 4);
    const float4 e2 = *(const float4*)(er + kc + 8);
    const float4 e3 = *(const float4*)(er + kc + 12);
    const float e[16] = {e0.x, e0.y, e0.z, e0.w, e1.x, e1.y, e1.z, e1.w,
                         e2.x, e2.y, e2.z, e2.w, e3.x, e3.y, e3.z, e3.w};
#pragma unroll
    for (int j = 0; j < 4; ++j) {
      const float* w = w_ih + (size_t)(j0 + j) * 1024 + kc;  // wave-uniform -> s_load
#pragma unroll
      for (int i = 0; i < 16; ++i) acc[j] = fmaf(e[i], w[i], acc[j]);
    }
  }
  *(float4*)(gi + (size_t)t * 3072 + j0) = make_float4(acc[0], acc[1], acc[2], acc[3]);
}

// ---------- K2: persistent recurrence ----------
// grid 128 x 512 (8 waves). Wave wv of block g owns h element hj = 8g+wv; its three
// w_hh rows (r,z,n) live in 48 fp32 VGPRs per lane (no LDS weight traffic per step).
// Sync: sentinel-in-data. Producers (lane 0) store h bits with a relaxed agent atomic
// (sc0 sc1 -> L3 coherence point). Each wave polls only ITS 128-word chunk of h[t-1]
// with ONE coalesced u64 relaxed-agent atomic load per lane per round (always fresh at
// L3; no buffer_inv storm, gi/w_out scalar loads stay cached), then fills its hlds
// chunk in parallel. barrier1 = whole hlds valid; barrier2 (end of step) guards the
// WAR hazard chunk-fill(t+1) vs hlds-reads(t) (chunk-complete no longer implies this
// block's dots are done, unlike the full-row poll).
__global__ __launch_bounds__(512) void k2_rec(const float* __restrict__ w_hh,
                                              const float* __restrict__ b_hh,
                                              const float* __restrict__ gi,
                                              const float* __restrict__ w_out,
                                              unsigned int* __restrict__ hseq,
                                              float* __restrict__ acc)
{
  __shared__ float hlds[1024];   // 4 KB only

  const int g    = blockIdx.x;
  const int tid  = threadIdx.x;
  const int wv   = tid >> 6;
  const int lane = tid & 63;
  const int hj   = __builtin_amdgcn_readfirstlane(g * 8 + wv);  // uniform -> s_loads

  // ---- weights into VGPRs: w[gate*4+j] holds row[j*256 + lane*4 .. +3] ----
  float4 w[12];
#pragma unroll
  for (int gate = 0; gate < 3; ++gate) {
    const float* row = w_hh + (size_t)(gate * 1024 + hj) * 1024;
#pragma unroll
    for (int j = 0; j < 4; ++j)
      w[gate * 4 + j] = *(const float4*)(row + j * 256 + lane * 4);
  }
  const float bhh_n = b_hh[2048 + hj];
  float hp = 0.0f, wout_acc = 0.0f;

  const unsigned long long* hs64 = (const unsigned long long*)hseq;

#pragma unroll 1
  for (int t = 0; t < 256; ++t) {
    // wave-uniform scalar prefetches (overlap the poll round-trip)
    const float gi_r = gi[(size_t)t * 3072 + hj];
    const float gi_z = gi[(size_t)t * 3072 + 1024 + hj];
    const float gi_n = gi[(size_t)t * 3072 + 2048 + hj];
    const float wo   = w_out[(size_t)t * 1024 + hj];

    float ar = 0.f, az = 0.f, an = 0.f;

    if (t > 0) {
      // poll own 512 B chunk of row t-1: one u64 atomic load per lane per round
      const unsigned long long* p = hs64 + (size_t)(t - 1) * 512 + wv * 64 + lane;
      unsigned long long v;
      for (;;) {
        v = __hip_atomic_load(p, __ATOMIC_RELAXED, __HIP_MEMORY_SCOPE_AGENT);
        const bool ok = (((unsigned int)v) != SENT) &
                        (((unsigned int)(v >> 32)) != SENT);
        if (__all(ok)) break;
      }
      const int w0 = wv * 128 + lane * 2;          // 8B-aligned -> ds_write_b64
      hlds[w0]     = __uint_as_float((unsigned int)v);
      hlds[w0 + 1] = __uint_as_float((unsigned int)(v >> 32));
      __syncthreads();                              // barrier1: hlds fully valid

      // dot: lane owns k = j*256 + lane*4 + c
#pragma unroll
      for (int j = 0; j < 4; ++j) {
        const float4 h4 = *(const float4*)&hlds[j * 256 + lane * 4];
        const float4 wr = w[j], wz = w[4 + j], wn = w[8 + j];
        ar = fmaf(h4.x, wr.x, ar); ar = fmaf(h4.y, wr.y, ar);
        ar = fmaf(h4.z, wr.z, ar); ar = fmaf(h4.w, wr.w, ar);
        az = fmaf(h4.x, wz.x, az); az = fmaf(h4.y, wz.y, az);
        az = fmaf(h4.z, wz.z, az); az = fmaf(h4.w, wz.w, az);
        an = fmaf(h4.x, wn.x, an); an = fmaf(h4.y, wn.y, an);
        an = fmaf(h4.z, wn.z, an); an = fmaf(h4.w, wn.w, an);
      }
#pragma unroll
      for (int m = 1; m < 64; m <<= 1) {
        ar += __shfl_xor(ar, m, 64);
        az += __shfl_xor(az, m, 64);
        an += __shfl_xor(an, m, 64);
      }
    }

    const float r  = sigf(ar + gi_r);               // b_ih+b_hh folded into gi_r/gi_z
    const float z  = sigf(az + gi_z);
    const float n  = tanh_fast(gi_n + r * (an + bhh_n));
    const float h2 = (1.0f - z) * n + z * hp;

    unsigned int bits = __float_as_uint(h2);
    if (bits == SENT) bits ^= 1u;                   // never store the sentinel
    if (lane == 0) {
      __hip_atomic_store(hseq + (size_t)t * 1024 + hj, bits, __ATOMIC_RELAXED,
                         __HIP_MEMORY_SCOPE_AGENT);
      wout_acc = fmaf(__uint_as_float(bits), wo, wout_acc);  // fold w_out dot in
    }
    hp = __uint_as_float(bits);

    if (t > 0) __syncthreads();  // barrier2: hlds reads(t) done before fill(t+1)
  }

  if (lane == 0) atomicAdd(acc, wout_acc);
}

// ---------- K3: pure feat broadcast: feat[b][i] = hseq[i] for all 64 b ----------
__global__ __launch_bounds__(256) void k3_bcast(const float* __restrict__ hseq_f,
                                                float* __restrict__ outbuf)
{
  const int gtid = blockIdx.x * 256 + threadIdx.x;
  const float4* src = (const float4*)hseq_f;    // 65536 float4
  float4* dst = (float4*)outbuf;
  for (int q = gtid; q < 64 * 65536; q += 1024 * 256) {
    const int b = q >> 16, i4 = q & 65535;
    dst[(size_t)b * 65536 + i4] = src[i4];
  }
}

// ---------- K4: out[b] = sigmoid(acc + b_out) for all 64 b ----------
__global__ void k4_fin(const float* __restrict__ acc, const float* __restrict__ b_out,
                       float* __restrict__ outbuf)
{
  const float s = sigf(acc[0] + b_out[0]);
  outbuf[(size_t)16777216 + threadIdx.x] = s;
}

// ---------- launch ----------
extern "C" void kernel_launch(void* const* d_in, const int* in_sizes, int n_in,
                              void* d_out, int out_size, void* d_ws, size_t ws_size,
                              hipStream_t stream) {
  const int*   x     = (const int*)d_in[0];
  const float* emb   = (const float*)d_in[1];
  const float* w_ih  = (const float*)d_in[2];
  const float* w_hh  = (const float*)d_in[3];
  const float* b_ih  = (const float*)d_in[4];
  const float* b_hh  = (const float*)d_in[5];
  const float* w_out = (const float*)d_in[6];
  const float* b_out = (const float*)d_in[7];
  float* out = (float*)d_out;

  char* ws = (char*)d_ws;
  float*        gi   = (float*)ws;                       // 3,145,728 B
  unsigned int* hseq = (unsigned int*)(ws + 3145728);    // 1,048,576 B
  float*        acc  = (float*)(ws + 4194304);           // 4 B

  hipMemsetAsync(hseq, 0xAA, (size_t)256 * 1024 * 4, stream);  // sentinel init
  hipMemsetAsync(acc, 0, 4, stream);

  hipLaunchKernelGGL(k1_gi,    dim3(768),  dim3(256), 0, stream, x, emb, w_ih, b_ih, b_hh, gi);
  hipLaunchKernelGGL(k2_rec,   dim3(128),  dim3(512), 0, stream, w_hh, b_hh, gi, w_out, hseq, acc);
  hipLaunchKernelGGL(k3_bcast, dim3(1024), dim3(256), 0, stream, (const float*)hseq, out);
  hipLaunchKernelGGL(k4_fin,   dim3(1),    dim3(64),  0, stream, acc, b_out, out);
}